// Round 2
// baseline (440.763 us; speedup 1.0000x reference)
//
#include <hip/hip_runtime.h>
#include <hip/hip_bf16.h>
#include <math.h>

#define S_LEN   4096
#define B_SZ    32
#define D_DIM   64
#define L_LNK   13
#define NW_R    13
#define HF_W    128
#define HV_W    128
#define VOCAB_N 512
#define NC_N    2
#define SMASK   4095

__device__ __forceinline__ float gelu_erf(float x) {
    return 0.5f * x * (1.0f + erff(x * 0.70710678118654752440f));
}

__device__ __forceinline__ void fma4(float4& a, float s, float4 z) {
    a.x += s * z.x; a.y += s * z.y; a.z += s * z.z; a.w += s * z.w;
}

// bf16x4 pack/unpack: element order = {lo16(u.x), hi16(u.x), lo16(u.y), hi16(u.y)}
__device__ __forceinline__ uint2 pack4(float4 v) {
    __hip_bfloat162 a = __float22bfloat162_rn(float2{v.x, v.y});
    __hip_bfloat162 b = __float22bfloat162_rn(float2{v.z, v.w});
    uint2 r;
    r.x = *reinterpret_cast<unsigned int*>(&a);
    r.y = *reinterpret_cast<unsigned int*>(&b);
    return r;
}

__device__ __forceinline__ float4 unpack4(uint2 u) {
    float4 r;
    r.x = __uint_as_float(u.x << 16);
    r.y = __uint_as_float(u.x & 0xffff0000u);
    r.z = __uint_as_float(u.y << 16);
    r.w = __uint_as_float(u.y & 0xffff0000u);
    return r;
}

// ---------------------------------------------------------------------------
// Kernel A: per-token tables (unchanged from R1).
// ---------------------------------------------------------------------------
__global__ __launch_bounds__(128)
void tables_kernel(const float* __restrict__ emb,
                   const float* __restrict__ fW1, const float* __restrict__ fb1,
                   const float* __restrict__ fW2, const float* __restrict__ fb2,
                   const float* __restrict__ vW1, const float* __restrict__ vb1,
                   const float* __restrict__ vW2, const float* __restrict__ vb2,
                   float* __restrict__ F_table, float* __restrict__ V_table) {
    __shared__ float s_emb[D_DIM];
    __shared__ float s_H[HF_W];
    const int blk = blockIdx.x;
    const int tid = threadIdx.x;

    if (blk < NW_R * VOCAB_N) {
        const int k = blk >> 9;
        const int t = blk & (VOCAB_N - 1);
        if (tid < D_DIM) s_emb[tid] = emb[t * D_DIM + tid];
        __syncthreads();
        float acc = fb1[k * HF_W + tid];
        const float* w = fW1 + (size_t)k * D_DIM * HF_W + tid;
        #pragma unroll 8
        for (int d = 0; d < D_DIM; ++d) acc += s_emb[d] * w[d * HF_W];
        s_H[tid] = gelu_erf(acc);
        __syncthreads();
        if (tid < 16) {
            float o = 0.0f;
            if (tid < L_LNK) {
                o = fb2[k * L_LNK + tid];
                const float* w2 = fW2 + (size_t)k * HF_W * L_LNK + tid;
                #pragma unroll 8
                for (int h = 0; h < HF_W; ++h) o += s_H[h] * w2[h * L_LNK];
            }
            F_table[((size_t)(k * VOCAB_N + t)) * 16 + tid] = o;
        }
    } else {
        const int t = blk - NW_R * VOCAB_N;
        if (tid < D_DIM) s_emb[tid] = emb[t * D_DIM + tid];
        __syncthreads();
        float acc = vb1[tid];
        const float* w = vW1 + tid;
        #pragma unroll 8
        for (int d = 0; d < D_DIM; ++d) acc += s_emb[d] * w[d * HV_W];
        s_H[tid] = gelu_erf(acc);
        __syncthreads();
        if (tid < D_DIM) {
            float o = vb2[tid];
            const float* w2 = vW2 + tid;
            #pragma unroll 8
            for (int h = 0; h < HV_W; ++h) o += s_H[h] * w2[h * D_DIM];
            V_table[t * D_DIM + tid] = o;
        }
    }
}

// ---------------------------------------------------------------------------
// Kernel B: logits. 64 blocks x 1024 threads (was 256 -> 1 wave/CU, latency
// bound). Each thread handles 4 rows; block tree-reduce.
// ---------------------------------------------------------------------------
__global__ __launch_bounds__(1024)
void logits_kernel(const int* __restrict__ tok,
                   const float* __restrict__ V_table,
                   const float* __restrict__ finW,
                   const float* __restrict__ finb,
                   float* __restrict__ out) {
    const int b = blockIdx.x >> 1;
    const int c = blockIdx.x & 1;
    const int tid = threadIdx.x;
    const float4* fin4 = (const float4*)(finW + (size_t)c * S_LEN * D_DIM);
    const float4* V4 = (const float4*)V_table;
    float acc = 0.0f;
    #pragma unroll
    for (int it = 0; it < 4; ++it) {
        const int s = tid + it * 1024;
        const int t = tok[b * S_LEN + s];
        const float4* vp = V4 + t * 16;
        const float4* fp = fin4 + s * 16;
        #pragma unroll
        for (int j = 0; j < 16; ++j) {
            float4 v = vp[j], f = fp[j];
            acc += v.x * f.x + v.y * f.y + v.z * f.z + v.w * f.w;
        }
    }
    #pragma unroll
    for (int o = 32; o > 0; o >>= 1) acc += __shfl_down(acc, o, 64);
    __shared__ float s_part[16];
    if ((tid & 63) == 0) s_part[tid >> 6] = acc;
    __syncthreads();
    if (tid == 0) {
        float s = finb[c];
        #pragma unroll
        for (int i = 0; i < 16; ++i) s += s_part[i];
        out[b * NC_N + c] = s;
    }
}

// ---------------------------------------------------------------------------
// Kernel C: chord sparse-multiply.
//  - Z stored bf16x4 (8 B/row-slice) in LDS, DOUBLE-buffered: 2 x 32 KB.
//  - One __syncthreads per round (write goes to the other buffer).
//  - Links 0 / 1024 / 2048 come from fp32 registers (thread t owns rows
//    t, t+1024, t+2048, t+3072 -> those offsets are zprev of another j).
//  - Accumulation and residual V stay fp32; only the 10 LDS-communicated
//    links are bf16-rounded (RNE). Error ~0.5% of |Z| vs 2% threshold.
// Grid: dim3(16, 32) x 1024 threads.
// ---------------------------------------------------------------------------
__global__ __launch_bounds__(1024)
void chord_kernel(const int* __restrict__ tok,
                  const float* __restrict__ F_table,
                  const float* __restrict__ V_table,
                  float* __restrict__ Zout) {
    __shared__ uint2 Zs[2][S_LEN];   // 2 x 32768 B
    const int b = blockIdx.y;
    const int ds = blockIdx.x;
    const int t = threadIdx.x;
    const float4* V4 = (const float4*)V_table;

    int tokr[4];
    float4 Vr[4], zprev[4];
    #pragma unroll
    for (int j = 0; j < 4; ++j) {
        const int r = t + 1024 * j;
        const int tk = tok[b * S_LEN + r];
        tokr[j] = tk;
        float4 v = V4[tk * 16 + ds];
        Vr[j] = v;
        zprev[j] = v;
        Zs[0][r] = pack4(v);
    }
    __syncthreads();

    int cur = 0;
    for (int k = 0; k < NW_R; ++k) {
        float4 acc[4];
        #pragma unroll
        for (int j = 0; j < 4; ++j) {
            const int r = t + 1024 * j;
            const float* F =
                F_table + ((size_t)(k * VOCAB_N + tokr[j]) << 4);
            float4 f0 = ((const float4*)F)[0];   // offsets 0,1,2,4
            float4 f1 = ((const float4*)F)[1];   // offsets 8,16,32,64
            float4 f2 = ((const float4*)F)[2];   // offsets 128,256,512,1024
            float  f12 = F[12];                  // offset 2048

            float4 a = Vr[j];                         // residual
            fma4(a, f0.x, zprev[j]);                  // offset 0    (regs)
            fma4(a, f2.w, zprev[(j + 1) & 3]);        // offset 1024 (regs)
            fma4(a, f12,  zprev[(j + 2) & 3]);        // offset 2048 (regs)
            fma4(a, f0.y, unpack4(Zs[cur][(r + 1)   & SMASK]));
            fma4(a, f0.z, unpack4(Zs[cur][(r + 2)   & SMASK]));
            fma4(a, f0.w, unpack4(Zs[cur][(r + 4)   & SMASK]));
            fma4(a, f1.x, unpack4(Zs[cur][(r + 8)   & SMASK]));
            fma4(a, f1.y, unpack4(Zs[cur][(r + 16)  & SMASK]));
            fma4(a, f1.z, unpack4(Zs[cur][(r + 32)  & SMASK]));
            fma4(a, f1.w, unpack4(Zs[cur][(r + 64)  & SMASK]));
            fma4(a, f2.x, unpack4(Zs[cur][(r + 128) & SMASK]));
            fma4(a, f2.y, unpack4(Zs[cur][(r + 256) & SMASK]));
            fma4(a, f2.z, unpack4(Zs[cur][(r + 512) & SMASK]));
            acc[j] = a;
        }
        if (k < NW_R - 1) {
            #pragma unroll
            for (int j = 0; j < 4; ++j)
                Zs[cur ^ 1][t + 1024 * j] = pack4(acc[j]);
        }
        #pragma unroll
        for (int j = 0; j < 4; ++j) zprev[j] = acc[j];
        __syncthreads();
        cur ^= 1;
    }

    float4* Zo = (float4*)Zout;
    #pragma unroll
    for (int j = 0; j < 4; ++j) {
        const int r = t + 1024 * j;
        Zo[((size_t)b * S_LEN + r) * 16 + ds] = zprev[j];
    }
}

extern "C" void kernel_launch(void* const* d_in, const int* in_sizes, int n_in,
                              void* d_out, int out_size, void* d_ws, size_t ws_size,
                              hipStream_t stream) {
    const int*   tok  = (const int*)d_in[0];
    const float* emb  = (const float*)d_in[1];
    const float* fW1  = (const float*)d_in[2];
    const float* fb1  = (const float*)d_in[3];
    const float* fW2  = (const float*)d_in[4];
    const float* fb2  = (const float*)d_in[5];
    const float* vW1  = (const float*)d_in[6];
    const float* vb1  = (const float*)d_in[7];
    const float* vW2  = (const float*)d_in[8];
    const float* vb2  = (const float*)d_in[9];
    const float* finW = (const float*)d_in[10];
    const float* finb = (const float*)d_in[11];

    float* out = (float*)d_out;          // (B, NC) = 64 floats
    float* Z   = out + B_SZ * NC_N;      // (B, S, D) fp32

    float* V_table = (float*)d_ws;                       // 512*64 f32
    float* F_table = V_table + VOCAB_N * D_DIM;          // 13*512*16 f32

    tables_kernel<<<NW_R * VOCAB_N + VOCAB_N, 128, 0, stream>>>(
        emb, fW1, fb1, fW2, fb2, vW1, vb1, vW2, vb2, F_table, V_table);
    logits_kernel<<<B_SZ * NC_N, 1024, 0, stream>>>(tok, V_table, finW, finb, out);
    chord_kernel<<<dim3(16, B_SZ), 1024, 0, stream>>>(tok, F_table, V_table, Z);
}